// Round 1
// baseline (540.352 us; speedup 1.0000x reference)
//
#include <hip/hip_runtime.h>

#define NIMG 16
#define HH 512
#define WW 512
#define HW (HH * WW)
#define NHW (NIMG * HW)
#define TILE 64
#define TILE_AREA (TILE * TILE)

#define EPSV ((float)(216.0 / 24389.0))
#define KAPV ((float)(24389.0 / 27.0))

__device__ __forceinline__ float srgb2lin(float c) {
    return (c <= (float)0.04045) ? (c / (float)12.92)
                                 : powf((c + (float)0.055) / (float)1.055, (float)2.4);
}

__device__ __forceinline__ float fwd_f(float v) {
    return (v > EPSV) ? cbrtf(v) : (KAPV * v + 16.0f) / 116.0f;
}

__device__ __forceinline__ float labL(float r, float g, float b) {
    float rl = srgb2lin(r), gl = srgb2lin(g), bl = srgb2lin(b);
    float Y = (float)0.2126729 * rl + (float)0.7151522 * gl + (float)0.072175 * bl;
    return 116.0f * fwd_f(Y) - 16.0f;
}

__device__ __forceinline__ void lab_full(float r, float g, float b,
                                         float* L, float* A, float* B) {
    float rl = srgb2lin(r), gl = srgb2lin(g), bl = srgb2lin(b);
    float X = ((float)0.4124564 * rl + (float)0.3575761 * gl + (float)0.1804375 * bl) / (float)0.95047;
    float Y = ((float)0.2126729 * rl + (float)0.7151522 * gl + (float)0.072175  * bl);
    float Z = ((float)0.0193339 * rl + (float)0.119192  * gl + (float)0.9503041 * bl) / (float)1.08883;
    float fx = fwd_f(X), fy = fwd_f(Y), fz = fwd_f(Z);
    *L = 116.0f * fy - 16.0f;
    *A = 500.0f * (fx - fy);
    *B = 200.0f * (fy - fz);
}

__device__ __forceinline__ float finv(float f) {
    float f3 = f * f * f;
    return (f3 > EPSV) ? f3 : (116.0f * f - 16.0f) / KAPV;
}

__device__ __forceinline__ float lin2srgb(float c) {
    c = fmaxf(c, 0.0f);
    float r = (c <= (float)0.0031308) ? (c * (float)12.92)
                                      : ((float)1.055 * powf(c, (float)(1.0 / 2.4)) - (float)0.055);
    return fminf(fmaxf(r, 0.0f), 1.0f);
}

__device__ __forceinline__ void lab2rgb255(float L, float a, float b,
                                           float* R, float* G, float* B) {
    float fy = (L + 16.0f) / 116.0f;
    float fx = fy + a / 500.0f;
    float fz = fy - b / 200.0f;
    float X = finv(fx) * (float)0.95047;
    float Y = finv(fy);
    float Z = finv(fz) * (float)1.08883;
    *R = lin2srgb((float)3.2404542 * X + (float)-1.5371385 * Y + (float)-0.4985314 * Z) * 255.0f;
    *G = lin2srgb((float)-0.969266 * X + (float)1.8760108  * Y + (float)0.041556   * Z) * 255.0f;
    *B = lin2srgb((float)0.0556434 * X + (float)-0.2040259 * Y + (float)1.0572252  * Z) * 255.0f;
}

__global__ void k_init(float* lminmax) {
    int t = threadIdx.x;
    if (t < 16)
        ((int*)lminmax)[t] = 0x7F7FFFFF;   // +FLT_MAX bits (min identity)
    else if (t < 32)
        ((int*)lminmax)[t] = 0;            // 0.0f (max identity; L >= 0)
}

__global__ void k_minmax(const float* __restrict__ x, float* __restrict__ lminmax) {
    int n = blockIdx.y;
    int p = blockIdx.x * 256 + threadIdx.x;
    const float* img = x + (size_t)n * 3 * HW;
    float L = labL(img[p], img[HW + p], img[2 * HW + p]);
    float mn = L, mx = L;
    for (int off = 32; off > 0; off >>= 1) {
        mn = fminf(mn, __shfl_down(mn, off, 64));
        mx = fmaxf(mx, __shfl_down(mx, off, 64));
    }
    __shared__ float smn[4], smx[4];
    int wave = threadIdx.x >> 6, lane = threadIdx.x & 63;
    if (lane == 0) { smn[wave] = mn; smx[wave] = mx; }
    __syncthreads();
    if (threadIdx.x == 0) {
        mn = fminf(fminf(smn[0], smn[1]), fminf(smn[2], smn[3]));
        mx = fmaxf(fmaxf(smx[0], smx[1]), fmaxf(smx[2], smx[3]));
        atomicMin((int*)&lminmax[n], __float_as_int(mn));
        atomicMax((int*)&lminmax[16 + n], __float_as_int(mx));
    }
}

__global__ void k_quant_hist(const float* __restrict__ x, const float* __restrict__ lminmax,
                             unsigned char* __restrict__ li_arr, int* __restrict__ hist_eq,
                             int* __restrict__ hist_tile) {
    int n = blockIdx.y, tile = blockIdx.x;
    int ty = tile >> 3, tx = tile & 7;
    __shared__ int sh[256];
    sh[threadIdx.x] = 0;
    __syncthreads();
    float lmin = lminmax[n], lmax = lminmax[16 + n];
    float d = lmax - lmin + (float)1e-6;
    const float* img = x + (size_t)n * 3 * HW;
    unsigned char* lio = li_arr + (size_t)n * HW;
    for (int i = threadIdx.x; i < TILE_AREA; i += 256) {
        int r = i >> 6, c = i & 63;
        int p = (ty * TILE + r) * WW + tx * TILE + c;
        float L = labL(img[p], img[HW + p], img[2 * HW + p]);
        float l255 = (L - lmin) / d * 255.0f;
        int li = (int)rintf(l255);
        li = min(max(li, 0), 255);
        lio[p] = (unsigned char)li;
        atomicAdd(&sh[li], 1);
    }
    __syncthreads();
    int h = sh[threadIdx.x];
    hist_tile[(n * 64 + tile) * 256 + threadIdx.x] = h;
    atomicAdd(&hist_eq[n * 256 + threadIdx.x], h);
}

__global__ void k_eq_lut(const int* __restrict__ hist_eq, float* __restrict__ lut_eq) {
    int n = blockIdx.x, t = threadIdx.x;
    __shared__ int s[256];
    s[t] = hist_eq[n * 256 + t];
    __syncthreads();
    for (int off = 1; off < 256; off <<= 1) {
        int v = s[t];
        int add = (t >= off) ? s[t - off] : 0;
        __syncthreads();
        s[t] = v + add;
        __syncthreads();
    }
    lut_eq[n * 256 + t] = rintf((float)s[t] * (float)(255.0 / (double)HW));
}

__global__ void k_clahe_lut(const int* __restrict__ hist_tile, float* __restrict__ lut_tile) {
    int b = blockIdx.y * 64 + blockIdx.x;
    int t = threadIdx.x;
    __shared__ int s[256];
    int h = hist_tile[b * 256 + t];
    int cl = min(h, 32);   // limit = max(2*4096/256, 1) = 32
    s[t] = cl;
    __syncthreads();
    for (int off = 1; off < 256; off <<= 1) {
        int v = s[t];
        int add = (t >= off) ? s[t - off] : 0;
        __syncthreads();
        s[t] = v + add;
        __syncthreads();
    }
    int cum = s[t];
    int total = s[255];
    float e = (float)(TILE_AREA - total) / 256.0f;
    float val = ((float)cum + (float)(t + 1) * e) * (float)(255.0 / 4096.0);
    lut_tile[b * 256 + t] = rintf(val);
}

__global__ void k_recon(const float* __restrict__ x, const unsigned char* __restrict__ li_arr,
                        const float* __restrict__ lut_eq, const float* __restrict__ lut_tile,
                        float* __restrict__ out) {
    int n = blockIdx.y;
    int p = blockIdx.x * 256 + threadIdx.x;
    int y = p >> 9, xc = p & 511;
    const float* img = x + (size_t)n * 3 * HW;
    float L, A, B;
    lab_full(img[p], img[HW + p], img[2 * HW + p], &L, &A, &B);
    int li = li_arr[(size_t)n * HW + p];
    float l_eq = lut_eq[n * 256 + li];

    float cyf = fminf(fmaxf(((float)y + 0.5f) / 64.0f - 0.5f, 0.0f), 7.0f);
    float cxf = fminf(fmaxf(((float)xc + 0.5f) / 64.0f - 0.5f, 0.0f), 7.0f);
    int y0 = min((int)cyf, 6), x0 = min((int)cxf, 6);
    float wy = cyf - (float)y0, wx = cxf - (float)x0;
    const float* lt = lut_tile + n * 64 * 256;
    float v00 = lt[((y0 * 8 + x0) << 8) + li];
    float v01 = lt[((y0 * 8 + x0 + 1) << 8) + li];
    float v10 = lt[(((y0 + 1) * 8 + x0) << 8) + li];
    float v11 = lt[(((y0 + 1) * 8 + x0 + 1) << 8) + li];
    float top = v00 * (1.0f - wx) + v01 * wx;
    float bot = v10 * (1.0f - wx) + v11 * wx;
    float l_cl = top * (1.0f - wy) + bot * wy;

    float* o0 = out + (size_t)n * 3 * HW;
    float* o1 = out + (size_t)3 * NHW + (size_t)n * 3 * HW;
    float R, G, Bc;
    lab2rgb255(l_eq * (float)(100.0 / 255.0), A, B, &R, &G, &Bc);
    o0[p] = R; o0[HW + p] = G; o0[2 * HW + p] = Bc;
    lab2rgb255(l_cl * (float)(100.0 / 255.0), A, B, &R, &G, &Bc);
    o1[p] = R; o1[HW + p] = G; o1[2 * HW + p] = Bc;
}

extern "C" void kernel_launch(void* const* d_in, const int* in_sizes, int n_in,
                              void* d_out, int out_size, void* d_ws, size_t ws_size,
                              hipStream_t stream) {
    const float* x = (const float*)d_in[0];
    float* out = (float*)d_out;
    char* ws = (char*)d_ws;

    unsigned char* li = (unsigned char*)ws;                 // NHW bytes = 4 MiB
    size_t off = (size_t)NHW;
    int* hist_eq = (int*)(ws + off);      off += NIMG * 256 * 4;          // 16 KiB
    int* hist_tile = (int*)(ws + off);    off += NIMG * 64 * 256 * 4;     // 1 MiB
    float* lut_eq = (float*)(ws + off);   off += NIMG * 256 * 4;
    float* lut_tile = (float*)(ws + off); off += NIMG * 64 * 256 * 4;
    float* lminmax = (float*)(ws + off);  off += 32 * 4;

    hipMemsetAsync(hist_eq, 0, (NIMG * 256 + NIMG * 64 * 256) * 4, stream);
    k_init<<<1, 32, 0, stream>>>(lminmax);
    k_minmax<<<dim3(HW / 256, NIMG), 256, 0, stream>>>(x, lminmax);
    k_quant_hist<<<dim3(64, NIMG), 256, 0, stream>>>(x, lminmax, li, hist_eq, hist_tile);
    k_eq_lut<<<NIMG, 256, 0, stream>>>(hist_eq, lut_eq);
    k_clahe_lut<<<dim3(64, NIMG), 256, 0, stream>>>(hist_tile, lut_tile);
    k_recon<<<dim3(HW / 256, NIMG), 256, 0, stream>>>(x, li, lut_eq, lut_tile, out);
}

// Round 2
// 341.935 us; speedup vs baseline: 1.5803x; 1.5803x over previous
//
#include <hip/hip_runtime.h>

#define NIMG 16
#define HH 512
#define WW 512
#define HW (HH * WW)
#define NHW (NIMG * HW)
#define TILE 64
#define TILE_AREA (TILE * TILE)

#define EPSV ((float)(216.0 / 24389.0))
#define KAPV ((float)(24389.0 / 27.0))

// ---------- fast transcendental helpers (v_log_f32 / v_exp_f32 based) ----------

// t^2.4 with ~3e-7 rel err: double-single refined log2, split exponent.
__device__ __forceinline__ float pow24(float t) {
    float l   = __builtin_amdgcn_logf(t);             // log2 approx (1 ULP)
    float r   = __builtin_amdgcn_exp2f(l);
    float dl  = (t - r) * __builtin_amdgcn_rcpf(r) * 1.4426950408889634f; // residual in log2
    float ehi = 2.4f * l;
    float elo = __builtin_fmaf(2.4f, l, -ehi) + 2.4f * dl;
    float p   = __builtin_amdgcn_exp2f(ehi);
    return __builtin_fmaf(p * 0.6931471805599453f, elo, p);  // p * (1 + elo*ln2)
}

// cbrt with Newton polish, ~1e-7 rel err (v > 0 on live path)
__device__ __forceinline__ float cbrt_p(float v) {
    float l  = __builtin_amdgcn_logf(v);
    float t  = __builtin_amdgcn_exp2f(l * (1.0f / 3.0f));
    float t2 = t * t;
    float num = __builtin_fmaf(-t2, t, v);            // v - t^3
    return __builtin_fmaf(num, __builtin_amdgcn_rcpf(3.0f * t2), t);
}

__device__ __forceinline__ float srgb2lin_p(float c) {
    float lin = c / 12.92f;                           // precise div (matches ref rounding)
    float t   = (c + 0.055f) / 1.055f;                // precise div
    return (c <= 0.04045f) ? lin : pow24(t);
}

__device__ __forceinline__ float fwd_p(float v) {
    return (v > EPSV) ? cbrt_p(v) : (KAPV * v + 16.0f) / 116.0f;
}

// fast x^(1/2.4) for output path (continuous, err ~5e-7 rel)
__device__ __forceinline__ float lin2srgb_f(float c) {
    c = fmaxf(c, 0.0f);
    float lo = c * 12.92f;
    float p  = __builtin_amdgcn_exp2f(__builtin_amdgcn_logf(c) * (float)(1.0 / 2.4));
    float hi = 1.055f * p - 0.055f;
    float r  = (c <= 0.0031308f) ? lo : hi;
    return fminf(fmaxf(r, 0.0f), 1.0f);
}

__device__ __forceinline__ float finv_f(float f) {
    float f3 = f * f * f;
    return (f3 > EPSV) ? f3 : (116.0f * f - 16.0f) * (float)(27.0 / 24389.0);
}

__device__ __forceinline__ void lab2rgb255_f(float L, float a, float b,
                                             float* R, float* G, float* B) {
    float fy = (L + 16.0f) * (float)(1.0 / 116.0);
    float fx = fy + a * (float)(1.0 / 500.0);
    float fz = fy - b * (float)(1.0 / 200.0);
    float X = finv_f(fx) * 0.95047f;
    float Y = finv_f(fy);
    float Z = finv_f(fz) * 1.08883f;
    *R = lin2srgb_f((float)3.2404542 * X + (float)-1.5371385 * Y + (float)-0.4985314 * Z) * 255.0f;
    *G = lin2srgb_f((float)-0.969266 * X + (float)1.8760108  * Y + (float)0.041556   * Z) * 255.0f;
    *B = lin2srgb_f((float)0.0556434 * X + (float)-0.2040259 * Y + (float)1.0572252  * Z) * 255.0f;
}

// monotone float<->uint key for min/max atomics
__device__ __forceinline__ unsigned f2o(float f) {
    unsigned b = __float_as_uint(f);
    return (b & 0x80000000u) ? ~b : (b | 0x80000000u);
}
__device__ __forceinline__ float o2f(unsigned o) {
    return __uint_as_float((o & 0x80000000u) ? (o ^ 0x80000000u) : ~o);
}

// ---------- kernels ----------

__global__ void k_init(unsigned* mmkeys) {
    int t = threadIdx.x;
    if (t < 16) mmkeys[t] = 0xFFFFFFFFu;   // min identity
    else if (t < 32) mmkeys[t] = 0u;       // max identity
}

// Lab once: L,a,b written into d_out (output-0 region, channels 0/1/2), min/max reduce.
__global__ void k_lab(const float* __restrict__ x, float* __restrict__ out,
                      unsigned* __restrict__ mmkeys) {
    int n = blockIdx.y;
    int p = blockIdx.x * 256 + threadIdx.x;
    const float* img = x + (size_t)n * 3 * HW;
    float rl = srgb2lin_p(img[p]);
    float gl = srgb2lin_p(img[HW + p]);
    float bl = srgb2lin_p(img[2 * HW + p]);
    float X = ((float)0.4124564 * rl + (float)0.3575761 * gl + (float)0.1804375 * bl) / (float)0.95047;
    float Y = ((float)0.2126729 * rl + (float)0.7151522 * gl + (float)0.072175  * bl);
    float Z = ((float)0.0193339 * rl + (float)0.119192  * gl + (float)0.9503041 * bl) / (float)1.08883;
    float fx = fwd_p(X), fy = fwd_p(Y), fz = fwd_p(Z);
    float L = 116.0f * fy - 16.0f;
    float* o = out + (size_t)n * 3 * HW;
    o[p]          = L;
    o[HW + p]     = 500.0f * (fx - fy);
    o[2 * HW + p] = 200.0f * (fy - fz);

    float mn = L, mx = L;
    for (int off = 32; off; off >>= 1) {
        mn = fminf(mn, __shfl_down(mn, off, 64));
        mx = fmaxf(mx, __shfl_down(mx, off, 64));
    }
    __shared__ float smn[4], smx[4];
    int wv = threadIdx.x >> 6, ln = threadIdx.x & 63;
    if (ln == 0) { smn[wv] = mn; smx[wv] = mx; }
    __syncthreads();
    if (threadIdx.x == 0) {
        mn = fminf(fminf(smn[0], smn[1]), fminf(smn[2], smn[3]));
        mx = fmaxf(fmaxf(smx[0], smx[1]), fmaxf(smx[2], smx[3]));
        atomicMin(&mmkeys[n], f2o(mn));
        atomicMax(&mmkeys[16 + n], f2o(mx));
    }
}

__global__ void k_quant_hist(const float* __restrict__ out, const unsigned* __restrict__ mmkeys,
                             unsigned char* __restrict__ li_arr, int* __restrict__ hist_eq,
                             int* __restrict__ hist_tile) {
    int n = blockIdx.y, tile = blockIdx.x;
    int ty = tile >> 3, tx = tile & 7;
    __shared__ int sh[256];
    sh[threadIdx.x] = 0;
    __syncthreads();
    float lmin = o2f(mmkeys[n]), lmax = o2f(mmkeys[16 + n]);
    float d = lmax - lmin + (float)1e-6;
    const float* Lp = out + (size_t)n * 3 * HW;   // channel 0 holds L
    unsigned char* lio = li_arr + (size_t)n * HW;
    for (int i = threadIdx.x; i < TILE_AREA; i += 256) {
        int r = i >> 6, c = i & 63;
        int p = (ty * TILE + r) * WW + tx * TILE + c;
        float L = Lp[p];
        float l255 = (L - lmin) / d * 255.0f;
        int li = (int)rintf(l255);
        li = min(max(li, 0), 255);
        lio[p] = (unsigned char)li;
        atomicAdd(&sh[li], 1);
    }
    __syncthreads();
    int h = sh[threadIdx.x];
    hist_tile[(n * 64 + tile) * 256 + threadIdx.x] = h;
    atomicAdd(&hist_eq[n * 256 + threadIdx.x], h);
}

__global__ void k_eq_lut(const int* __restrict__ hist_eq, float* __restrict__ lut_eq) {
    int n = blockIdx.x, t = threadIdx.x;
    __shared__ int s[256];
    s[t] = hist_eq[n * 256 + t];
    __syncthreads();
    for (int off = 1; off < 256; off <<= 1) {
        int v = s[t];
        int add = (t >= off) ? s[t - off] : 0;
        __syncthreads();
        s[t] = v + add;
        __syncthreads();
    }
    lut_eq[n * 256 + t] = rintf((float)s[t] * (float)(255.0 / (double)HW));
}

__global__ void k_clahe_lut(const int* __restrict__ hist_tile, float* __restrict__ lut_tile) {
    int b = blockIdx.y * 64 + blockIdx.x;
    int t = threadIdx.x;
    __shared__ int s[256];
    int h = hist_tile[b * 256 + t];
    int cl = min(h, 32);   // limit = max(2*4096/256, 1) = 32
    s[t] = cl;
    __syncthreads();
    for (int off = 1; off < 256; off <<= 1) {
        int v = s[t];
        int add = (t >= off) ? s[t - off] : 0;
        __syncthreads();
        s[t] = v + add;
        __syncthreads();
    }
    int cum = s[t];
    int total = s[255];
    float e = (float)(TILE_AREA - total) / 256.0f;
    float val = ((float)cum + (float)(t + 1) * e) * (float)(255.0 / 4096.0);
    lut_tile[b * 256 + t] = rintf(val);
}

// One block per 64x64 tile; stages 9 neighbor tile-LUTs + eq-LUT in LDS.
// Reads a,b (and li) for its own pixels from d_out, then overwrites both outputs.
__global__ void k_recon(const unsigned char* __restrict__ li_arr,
                        const float* __restrict__ lut_eq,
                        const float* __restrict__ lut_tile,
                        float* __restrict__ out) {
    int n = blockIdx.y, tile = blockIdx.x;
    int ty = tile >> 3, tx = tile & 7;
    __shared__ float slut[9 * 256];
    __shared__ float seq[256];
    seq[threadIdx.x] = lut_eq[n * 256 + threadIdx.x];
    const float* lt = lut_tile + n * 64 * 256;
    for (int j = threadIdx.x; j < 9 * 256; j += 256) {
        int q = j >> 8;
        int jy = q / 3, jx = q % 3;
        int gy = min(max(ty - 1 + jy, 0), 7);
        int gx = min(max(tx - 1 + jx, 0), 7);
        slut[j] = lt[(gy * 8 + gx) * 256 + (j & 255)];
    }
    __syncthreads();

    float* o0 = out + (size_t)n * 3 * HW;
    float* o1 = out + (size_t)3 * NHW + (size_t)n * 3 * HW;
    const unsigned char* lip = li_arr + (size_t)n * HW;

    for (int i = threadIdx.x; i < TILE_AREA; i += 256) {
        int r = i >> 6, c = i & 63;
        int y = ty * TILE + r, xc = tx * TILE + c;
        int p = y * WW + xc;
        float a  = o0[HW + p];
        float b2 = o0[2 * HW + p];
        int li = lip[p];
        float l_eq = seq[li];

        float cyf = fminf(fmaxf(((float)y + 0.5f) / 64.0f - 0.5f, 0.0f), 7.0f);
        float cxf = fminf(fmaxf(((float)xc + 0.5f) / 64.0f - 0.5f, 0.0f), 7.0f);
        int y0 = min((int)cyf, 6), x0 = min((int)cxf, 6);
        float wy = cyf - (float)y0, wx = cxf - (float)x0;
        int ly = y0 - ty + 1, lx = x0 - tx + 1;
        int base = ((ly * 3 + lx) << 8) + li;
        float v00 = slut[base];
        float v01 = slut[base + 256];
        float v10 = slut[base + 768];
        float v11 = slut[base + 1024];
        float top = v00 * (1.0f - wx) + v01 * wx;
        float bot = v10 * (1.0f - wx) + v11 * wx;
        float l_cl = top * (1.0f - wy) + bot * wy;

        float R, G, B;
        lab2rgb255_f(l_eq * (float)(100.0 / 255.0), a, b2, &R, &G, &B);
        o0[p] = R; o0[HW + p] = G; o0[2 * HW + p] = B;
        lab2rgb255_f(l_cl * (float)(100.0 / 255.0), a, b2, &R, &G, &B);
        o1[p] = R; o1[HW + p] = G; o1[2 * HW + p] = B;
    }
}

extern "C" void kernel_launch(void* const* d_in, const int* in_sizes, int n_in,
                              void* d_out, int out_size, void* d_ws, size_t ws_size,
                              hipStream_t stream) {
    const float* x = (const float*)d_in[0];
    float* out = (float*)d_out;
    char* ws = (char*)d_ws;

    unsigned char* li = (unsigned char*)ws;          // 4 MiB
    size_t off = (size_t)NHW;
    int* hist_eq = (int*)(ws + off);      off += NIMG * 256 * 4;
    int* hist_tile = (int*)(ws + off);    off += NIMG * 64 * 256 * 4;
    float* lut_eq = (float*)(ws + off);   off += NIMG * 256 * 4;
    float* lut_tile = (float*)(ws + off); off += NIMG * 64 * 256 * 4;
    unsigned* mmkeys = (unsigned*)(ws + off); off += 32 * 4;

    hipMemsetAsync(hist_eq, 0, (NIMG * 256 + NIMG * 64 * 256) * 4, stream);
    k_init<<<1, 64, 0, stream>>>(mmkeys);
    k_lab<<<dim3(HW / 256, NIMG), 256, 0, stream>>>(x, out, mmkeys);
    k_quant_hist<<<dim3(64, NIMG), 256, 0, stream>>>(out, mmkeys, li, hist_eq, hist_tile);
    k_eq_lut<<<NIMG, 256, 0, stream>>>(hist_eq, lut_eq);
    k_clahe_lut<<<dim3(64, NIMG), 256, 0, stream>>>(hist_tile, lut_tile);
    k_recon<<<dim3(64, NIMG), 256, 0, stream>>>(li, lut_eq, lut_tile, out);
}

// Round 3
// 189.343 us; speedup vs baseline: 2.8538x; 1.8059x over previous
//
#include <hip/hip_runtime.h>

#define NIMG 16
#define HH 512
#define WW 512
#define HW (HH * WW)
#define NHW (NIMG * HW)
#define TILE 64
#define TILE_AREA (TILE * TILE)

#define EPSV ((float)(216.0 / 24389.0))
#define KAPV ((float)(24389.0 / 27.0))

// ---------- fast transcendental helpers (v_log_f32 / v_exp_f32 based) ----------

// t^2.4 with ~3e-7 rel err: double-single refined log2, split exponent.
__device__ __forceinline__ float pow24(float t) {
    float l   = __builtin_amdgcn_logf(t);
    float r   = __builtin_amdgcn_exp2f(l);
    float dl  = (t - r) * __builtin_amdgcn_rcpf(r) * 1.4426950408889634f;
    float ehi = 2.4f * l;
    float elo = __builtin_fmaf(2.4f, l, -ehi) + 2.4f * dl;
    float p   = __builtin_amdgcn_exp2f(ehi);
    return __builtin_fmaf(p * 0.6931471805599453f, elo, p);
}

// cbrt with Newton polish, ~1e-7 rel err (v > 0 on live path)
__device__ __forceinline__ float cbrt_p(float v) {
    float l  = __builtin_amdgcn_logf(v);
    float t  = __builtin_amdgcn_exp2f(l * (1.0f / 3.0f));
    float t2 = t * t;
    float num = __builtin_fmaf(-t2, t, v);
    return __builtin_fmaf(num, __builtin_amdgcn_rcpf(3.0f * t2), t);
}

__device__ __forceinline__ float srgb2lin_p(float c) {
    float lin = c / 12.92f;
    float t   = (c + 0.055f) / 1.055f;
    return (c <= 0.04045f) ? lin : pow24(t);
}

__device__ __forceinline__ float fwd_p(float v) {
    return (v > EPSV) ? cbrt_p(v) : (KAPV * v + 16.0f) / 116.0f;
}

__device__ __forceinline__ float lin2srgb_f(float c) {
    c = fmaxf(c, 0.0f);
    float lo = c * 12.92f;
    float p  = __builtin_amdgcn_exp2f(__builtin_amdgcn_logf(c) * (float)(1.0 / 2.4));
    float hi = 1.055f * p - 0.055f;
    float r  = (c <= 0.0031308f) ? lo : hi;
    return fminf(fmaxf(r, 0.0f), 1.0f);
}

__device__ __forceinline__ float finv_f(float f) {
    float f3 = f * f * f;
    return (f3 > EPSV) ? f3 : (116.0f * f - 16.0f) * (float)(27.0 / 24389.0);
}

__device__ __forceinline__ void lab2rgb255_f(float L, float a, float b,
                                             float* R, float* G, float* B) {
    float fy = (L + 16.0f) * (float)(1.0 / 116.0);
    float fx = fy + a * (float)(1.0 / 500.0);
    float fz = fy - b * (float)(1.0 / 200.0);
    float X = finv_f(fx) * 0.95047f;
    float Y = finv_f(fy);
    float Z = finv_f(fz) * 1.08883f;
    *R = lin2srgb_f((float)3.2404542 * X + (float)-1.5371385 * Y + (float)-0.4985314 * Z) * 255.0f;
    *G = lin2srgb_f((float)-0.969266 * X + (float)1.8760108  * Y + (float)0.041556   * Z) * 255.0f;
    *B = lin2srgb_f((float)0.0556434 * X + (float)-0.2040259 * Y + (float)1.0572252  * Z) * 255.0f;
}

// monotone float<->uint key for min/max atomics
__device__ __forceinline__ unsigned f2o(float f) {
    unsigned b = __float_as_uint(f);
    return (b & 0x80000000u) ? ~b : (b | 0x80000000u);
}
__device__ __forceinline__ float o2f(unsigned o) {
    return __uint_as_float((o & 0x80000000u) ? (o ^ 0x80000000u) : ~o);
}

// mm layout: min key for image n at [n*64], max key at [n*64+32] (128-B line pad)

__global__ void k_init(unsigned* mm) {
    int t = blockIdx.x * 256 + threadIdx.x;
    if (t < NIMG * 64)
        mm[t] = ((t & 63) < 32) ? 0xFFFFFFFFu : 0u;
}

// Lab once: L,a,b written into d_out (output-0 region, ch 0/1/2); 8 px/thread.
__global__ void k_lab(const float* __restrict__ x, float* __restrict__ out,
                      unsigned* __restrict__ mm) {
    int n = blockIdx.y;
    const float* img = x + (size_t)n * 3 * HW;
    float* o = out + (size_t)n * 3 * HW;
    int base = blockIdx.x * 2048;
    float mn = 1e30f, mx = -1e30f;
    for (int i = 0; i < 8; i++) {
        int p = base + i * 256 + threadIdx.x;
        float rl = srgb2lin_p(img[p]);
        float gl = srgb2lin_p(img[HW + p]);
        float bl = srgb2lin_p(img[2 * HW + p]);
        float X = ((float)0.4124564 * rl + (float)0.3575761 * gl + (float)0.1804375 * bl) / (float)0.95047;
        float Y = ((float)0.2126729 * rl + (float)0.7151522 * gl + (float)0.072175  * bl);
        float Z = ((float)0.0193339 * rl + (float)0.119192  * gl + (float)0.9503041 * bl) / (float)1.08883;
        float fx = fwd_p(X), fy = fwd_p(Y), fz = fwd_p(Z);
        float L = 116.0f * fy - 16.0f;
        o[p]          = L;
        o[HW + p]     = 500.0f * (fx - fy);
        o[2 * HW + p] = 200.0f * (fy - fz);
        mn = fminf(mn, L);
        mx = fmaxf(mx, L);
    }
    for (int off = 32; off; off >>= 1) {
        mn = fminf(mn, __shfl_down(mn, off, 64));
        mx = fmaxf(mx, __shfl_down(mx, off, 64));
    }
    __shared__ float smn[4], smx[4];
    int wv = threadIdx.x >> 6, ln = threadIdx.x & 63;
    if (ln == 0) { smn[wv] = mn; smx[wv] = mx; }
    __syncthreads();
    if (threadIdx.x == 0) {
        mn = fminf(fminf(smn[0], smn[1]), fminf(smn[2], smn[3]));
        mx = fmaxf(fmaxf(smx[0], smx[1]), fmaxf(smx[2], smx[3]));
        atomicMin(&mm[n * 64], f2o(mn));
        atomicMax(&mm[n * 64 + 32], f2o(mx));
    }
}

// Per 64x64 tile: quantize L -> li, LDS histogram, store tile hist, and
// compute the CLAHE tile LUT in-place (sequential f32 cumsum on thread 0
// to exactly match np.cumsum's per-step rounding).
__global__ void k_quant_hist(const float* __restrict__ out, const unsigned* __restrict__ mm,
                             unsigned char* __restrict__ li_arr, int* __restrict__ hist_tile,
                             float* __restrict__ lut_tile) {
    int n = blockIdx.y, tile = blockIdx.x;
    int ty = tile >> 3, tx = tile & 7;
    int t = threadIdx.x;
    __shared__ int sh[256];
    __shared__ float slut[256];
    sh[t] = 0;
    __syncthreads();
    float lmin = o2f(mm[n * 64]), lmax = o2f(mm[n * 64 + 32]);
    float d = lmax - lmin + (float)1e-6;
    const float* Lp = out + (size_t)n * 3 * HW;
    unsigned char* lio = li_arr + (size_t)n * HW;
    for (int i = t; i < TILE_AREA; i += 256) {
        int r = i >> 6, c = i & 63;
        int p = (ty * TILE + r) * WW + tx * TILE + c;
        float l255 = (Lp[p] - lmin) / d * 255.0f;
        int li = (int)rintf(l255);
        li = min(max(li, 0), 255);
        lio[p] = (unsigned char)li;
        atomicAdd(&sh[li], 1);
    }
    __syncthreads();
    int h = sh[t];
    hist_tile[(n * 64 + tile) * 256 + t] = h;

    // block-reduce sum of clipped for excess
    int cl = min(h, 32);   // limit = max(2*4096/256, 1) = 32
    int sum = cl;
    for (int off = 32; off; off >>= 1) sum += __shfl_down(sum, off, 64);
    __shared__ int wsum[4];
    if ((t & 63) == 0) wsum[t >> 6] = sum;
    __syncthreads();
    if (t == 0) {
        int total = wsum[0] + wsum[1] + wsum[2] + wsum[3];
        float e = (float)(TILE_AREA - total) / 256.0f;   // excess/NBINS (exact)
        float c = 0.0f;
        for (int b = 0; b < 256; b++) {
            float term = (float)min(sh[b], 32) + e;      // elementwise add, 1 rounding
            c += term;                                   // sequential f32 cumsum
            slut[b] = rintf(c * (float)(255.0 / 4096.0));
        }
    }
    __syncthreads();
    lut_tile[(n * 64 + tile) * 256 + t] = slut[t];
}

// Sum 64 tile hists -> per-image hist (int-exact), scan, eq LUT.
__global__ void k_eq_lut(const int* __restrict__ hist_tile, float* __restrict__ lut_eq) {
    int n = blockIdx.x, t = threadIdx.x;
    const int* ht = hist_tile + n * 64 * 256;
    int h = 0;
    for (int tile = 0; tile < 64; tile++) h += ht[tile * 256 + t];
    __shared__ int s[256];
    s[t] = h;
    __syncthreads();
    for (int off = 1; off < 256; off <<= 1) {
        int v = s[t];
        int add = (t >= off) ? s[t - off] : 0;
        __syncthreads();
        s[t] = v + add;
        __syncthreads();
    }
    lut_eq[n * 256 + t] = rintf((float)s[t] * (float)(255.0 / (double)HW));
}

// One block per tile; 9 neighbor tile-LUTs + eq-LUT staged in LDS.
__global__ void k_recon(const unsigned char* __restrict__ li_arr,
                        const float* __restrict__ lut_eq,
                        const float* __restrict__ lut_tile,
                        float* __restrict__ out) {
    int n = blockIdx.y, tile = blockIdx.x;
    int ty = tile >> 3, tx = tile & 7;
    __shared__ float slut[9 * 256];
    __shared__ float seq[256];
    seq[threadIdx.x] = lut_eq[n * 256 + threadIdx.x];
    const float* lt = lut_tile + n * 64 * 256;
    for (int j = threadIdx.x; j < 9 * 256; j += 256) {
        int q = j >> 8;
        int jy = q / 3, jx = q % 3;
        int gy = min(max(ty - 1 + jy, 0), 7);
        int gx = min(max(tx - 1 + jx, 0), 7);
        slut[j] = lt[(gy * 8 + gx) * 256 + (j & 255)];
    }
    __syncthreads();

    float* o0 = out + (size_t)n * 3 * HW;
    float* o1 = out + (size_t)3 * NHW + (size_t)n * 3 * HW;
    const unsigned char* lip = li_arr + (size_t)n * HW;

    for (int i = threadIdx.x; i < TILE_AREA; i += 256) {
        int r = i >> 6, c = i & 63;
        int y = ty * TILE + r, xc = tx * TILE + c;
        int p = y * WW + xc;
        float a  = o0[HW + p];
        float b2 = o0[2 * HW + p];
        int li = lip[p];
        float l_eq = seq[li];

        float cyf = fminf(fmaxf(((float)y + 0.5f) / 64.0f - 0.5f, 0.0f), 7.0f);
        float cxf = fminf(fmaxf(((float)xc + 0.5f) / 64.0f - 0.5f, 0.0f), 7.0f);
        int y0 = min((int)cyf, 6), x0 = min((int)cxf, 6);
        float wy = cyf - (float)y0, wx = cxf - (float)x0;
        int ly = y0 - ty + 1, lx = x0 - tx + 1;
        int base = ((ly * 3 + lx) << 8) + li;
        float v00 = slut[base];
        float v01 = slut[base + 256];
        float v10 = slut[base + 768];
        float v11 = slut[base + 1024];
        float top = v00 * (1.0f - wx) + v01 * wx;
        float bot = v10 * (1.0f - wx) + v11 * wx;
        float l_cl = top * (1.0f - wy) + bot * wy;

        float R, G, B;
        lab2rgb255_f(l_eq * (float)(100.0 / 255.0), a, b2, &R, &G, &B);
        o0[p] = R; o0[HW + p] = G; o0[2 * HW + p] = B;
        lab2rgb255_f(l_cl * (float)(100.0 / 255.0), a, b2, &R, &G, &B);
        o1[p] = R; o1[HW + p] = G; o1[2 * HW + p] = B;
    }
}

extern "C" void kernel_launch(void* const* d_in, const int* in_sizes, int n_in,
                              void* d_out, int out_size, void* d_ws, size_t ws_size,
                              hipStream_t stream) {
    const float* x = (const float*)d_in[0];
    float* out = (float*)d_out;
    char* ws = (char*)d_ws;

    unsigned char* li = (unsigned char*)ws;              // 4 MiB
    size_t off = (size_t)NHW;
    int* hist_tile = (int*)(ws + off);    off += NIMG * 64 * 256 * 4;   // 1 MiB
    float* lut_eq = (float*)(ws + off);   off += NIMG * 256 * 4;
    float* lut_tile = (float*)(ws + off); off += NIMG * 64 * 256 * 4;   // 1 MiB
    unsigned* mm = (unsigned*)(ws + off); off += NIMG * 64 * 4;

    k_init<<<4, 256, 0, stream>>>(mm);
    k_lab<<<dim3(HW / 2048, NIMG), 256, 0, stream>>>(x, out, mm);
    k_quant_hist<<<dim3(64, NIMG), 256, 0, stream>>>(out, mm, li, hist_tile, lut_tile);
    k_eq_lut<<<NIMG, 256, 0, stream>>>(hist_tile, lut_eq);
    k_recon<<<dim3(64, NIMG), 256, 0, stream>>>(li, lut_eq, lut_tile, out);
}

// Round 4
// 185.672 us; speedup vs baseline: 2.9103x; 1.0198x over previous
//
#include <hip/hip_runtime.h>

#define NIMG 16
#define HH 512
#define WW 512
#define HW (HH * WW)
#define NHW (NIMG * HW)
#define TILE 64
#define TILE_AREA (TILE * TILE)

#define EPSV ((float)(216.0 / 24389.0))
#define KAPV ((float)(24389.0 / 27.0))

// ---------- fast transcendental helpers ----------

__device__ __forceinline__ float pow24(float t) {
    float l   = __builtin_amdgcn_logf(t);
    float r   = __builtin_amdgcn_exp2f(l);
    float dl  = (t - r) * __builtin_amdgcn_rcpf(r) * 1.4426950408889634f;
    float ehi = 2.4f * l;
    float elo = __builtin_fmaf(2.4f, l, -ehi) + 2.4f * dl;
    float p   = __builtin_amdgcn_exp2f(ehi);
    return __builtin_fmaf(p * 0.6931471805599453f, elo, p);
}

__device__ __forceinline__ float cbrt_p(float v) {
    float l  = __builtin_amdgcn_logf(v);
    float t  = __builtin_amdgcn_exp2f(l * (1.0f / 3.0f));
    float t2 = t * t;
    float num = __builtin_fmaf(-t2, t, v);
    return __builtin_fmaf(num, __builtin_amdgcn_rcpf(3.0f * t2), t);
}

__device__ __forceinline__ float srgb2lin_p(float c) {
    float lin = c / 12.92f;
    float t   = (c + 0.055f) / 1.055f;
    return (c <= 0.04045f) ? lin : pow24(t);
}

__device__ __forceinline__ float fwd_p(float v) {
    return (v > EPSV) ? cbrt_p(v) : (KAPV * v + 16.0f) / 116.0f;
}

__device__ __forceinline__ float lin2srgb_f(float c) {
    c = fmaxf(c, 0.0f);
    float lo = c * 12.92f;
    float p  = __builtin_amdgcn_exp2f(__builtin_amdgcn_logf(c) * (float)(1.0 / 2.4));
    float hi = 1.055f * p - 0.055f;
    float r  = (c <= 0.0031308f) ? lo : hi;
    return fminf(fmaxf(r, 0.0f), 1.0f);
}

__device__ __forceinline__ float finv_f(float f) {
    float f3 = f * f * f;
    return (f3 > EPSV) ? f3 : (116.0f * f - 16.0f) * (float)(27.0 / 24389.0);
}

__device__ __forceinline__ void lab2rgb255_f(float L, float a, float b,
                                             float* R, float* G, float* B) {
    float fy = (L + 16.0f) * (float)(1.0 / 116.0);
    float fx = fy + a * (float)(1.0 / 500.0);
    float fz = fy - b * (float)(1.0 / 200.0);
    float X = finv_f(fx) * 0.95047f;
    float Y = finv_f(fy);
    float Z = finv_f(fz) * 1.08883f;
    *R = lin2srgb_f((float)3.2404542 * X + (float)-1.5371385 * Y + (float)-0.4985314 * Z) * 255.0f;
    *G = lin2srgb_f((float)-0.969266 * X + (float)1.8760108  * Y + (float)0.041556   * Z) * 255.0f;
    *B = lin2srgb_f((float)0.0556434 * X + (float)-0.2040259 * Y + (float)1.0572252  * Z) * 255.0f;
}

// monotone float<->uint key for min/max atomics
__device__ __forceinline__ unsigned f2o(float f) {
    unsigned b = __float_as_uint(f);
    return (b & 0x80000000u) ? ~b : (b | 0x80000000u);
}
__device__ __forceinline__ float o2f(unsigned o) {
    return __uint_as_float((o & 0x80000000u) ? (o ^ 0x80000000u) : ~o);
}

// mm layout: min key for image n at [n*64], max key at [n*64+32] (128-B line pad)

__global__ void k_init(unsigned* mm) {
    int t = blockIdx.x * 256 + threadIdx.x;
    if (t < NIMG * 64)
        mm[t] = ((t & 63) < 32) ? 0xFFFFFFFFu : 0u;
}

// L only (float4 path); a,b are recomputed later in k_recon.
__global__ void k_lab(const float* __restrict__ x, float* __restrict__ Lbuf,
                      unsigned* __restrict__ mm) {
    int n = blockIdx.y;
    const float* img = x + (size_t)n * 3 * HW;
    float* Lp = Lbuf + (size_t)n * HW;
    int base = blockIdx.x * 2048;
    float mn = 1e30f, mx = -1e30f;
    for (int i = 0; i < 2; i++) {
        int p = base + i * 1024 + threadIdx.x * 4;
        float4 r4 = *(const float4*)(img + p);
        float4 g4 = *(const float4*)(img + HW + p);
        float4 b4 = *(const float4*)(img + 2 * HW + p);
        float4 L4;
        #pragma unroll
        for (int k = 0; k < 4; k++) {
            float rr = ((const float*)&r4)[k];
            float gg = ((const float*)&g4)[k];
            float bb = ((const float*)&b4)[k];
            float rl = srgb2lin_p(rr), gl = srgb2lin_p(gg), bl = srgb2lin_p(bb);
            float Y = ((float)0.2126729 * rl + (float)0.7151522 * gl + (float)0.072175  * bl);
            float L = 116.0f * fwd_p(Y) - 16.0f;
            ((float*)&L4)[k] = L;
            mn = fminf(mn, L);
            mx = fmaxf(mx, L);
        }
        *(float4*)(Lp + p) = L4;
    }
    for (int off = 32; off; off >>= 1) {
        mn = fminf(mn, __shfl_down(mn, off, 64));
        mx = fmaxf(mx, __shfl_down(mx, off, 64));
    }
    __shared__ float smn[4], smx[4];
    int wv = threadIdx.x >> 6, ln = threadIdx.x & 63;
    if (ln == 0) { smn[wv] = mn; smx[wv] = mx; }
    __syncthreads();
    if (threadIdx.x == 0) {
        mn = fminf(fminf(smn[0], smn[1]), fminf(smn[2], smn[3]));
        mx = fmaxf(fmaxf(smx[0], smx[1]), fmaxf(smx[2], smx[3]));
        atomicMin(&mm[n * 64], f2o(mn));
        atomicMax(&mm[n * 64 + 32], f2o(mx));
    }
}

// Per 64x64 tile: quantize, LDS hist, store tile hist, CLAHE LUT via exact
// integer scan in units of 1/256 (bit-identical to sequential f32 cumsum:
// every partial sum is a multiple of 2^-8 below 2^12 -> exactly representable).
__global__ void k_quant_hist(const float* __restrict__ Lbuf, const unsigned* __restrict__ mm,
                             unsigned char* __restrict__ li_arr, int* __restrict__ hist_tile,
                             float* __restrict__ lut_tile) {
    int n = blockIdx.y, tile = blockIdx.x;
    int ty = tile >> 3, tx = tile & 7;
    int t = threadIdx.x;
    __shared__ int sh[256];
    sh[t] = 0;
    __syncthreads();
    float lmin = o2f(mm[n * 64]), lmax = o2f(mm[n * 64 + 32]);
    float d = lmax - lmin + (float)1e-6;
    const float* Lp = Lbuf + (size_t)n * HW;
    unsigned char* lio = li_arr + (size_t)n * HW;
    for (int i = t; i < TILE_AREA; i += 256) {
        int r = i >> 6, c = i & 63;
        int p = (ty * TILE + r) * WW + tx * TILE + c;
        float l255 = (Lp[p] - lmin) / d * 255.0f;
        int li = (int)rintf(l255);
        li = min(max(li, 0), 255);
        lio[p] = (unsigned char)li;
        atomicAdd(&sh[li], 1);
    }
    __syncthreads();
    int h = sh[t];
    hist_tile[(n * 64 + tile) * 256 + t] = h;

    int cl = min(h, 32);   // limit = max(2*4096/256, 1) = 32
    int sum = cl;
    for (int off = 32; off; off >>= 1) sum += __shfl_down(sum, off, 64);
    __shared__ int wsum[4];
    if ((t & 63) == 0) wsum[t >> 6] = sum;
    __syncthreads();
    int total = wsum[0] + wsum[1] + wsum[2] + wsum[3];
    int exc = TILE_AREA - total;            // excess (int)
    sh[t] = 256 * cl + exc;                 // term * 256, exact
    __syncthreads();
    for (int off = 1; off < 256; off <<= 1) {
        int v = sh[t];
        int add = (t >= off) ? sh[t - off] : 0;
        __syncthreads();
        sh[t] = v + add;
        __syncthreads();
    }
    lut_tile[(n * 64 + tile) * 256 + t] =
        rintf((float)sh[t] * (float)(255.0 / 1048576.0));   // 255*2^-20, exact
}

// Sum 64 tile hists -> per-image hist (int-exact), scan, eq LUT.
__global__ void k_eq_lut(const int* __restrict__ hist_tile, float* __restrict__ lut_eq) {
    int n = blockIdx.x, t = threadIdx.x;
    const int* ht = hist_tile + n * 64 * 256;
    int h = 0;
    for (int tile = 0; tile < 64; tile++) h += ht[tile * 256 + t];
    __shared__ int s[256];
    s[t] = h;
    __syncthreads();
    for (int off = 1; off < 256; off <<= 1) {
        int v = s[t];
        int add = (t >= off) ? s[t - off] : 0;
        __syncthreads();
        s[t] = v + add;
        __syncthreads();
    }
    lut_eq[n * 256 + t] = rintf((float)s[t] * (float)(255.0 / (double)HW));
}

// One block per tile; recompute Lab from x; 9 neighbor LUTs + eq-LUT in LDS.
__global__ void k_recon(const float* __restrict__ x, const unsigned char* __restrict__ li_arr,
                        const float* __restrict__ lut_eq, const float* __restrict__ lut_tile,
                        float* __restrict__ out) {
    int n = blockIdx.y, tile = blockIdx.x;
    int ty = tile >> 3, tx = tile & 7;
    int t = threadIdx.x;
    __shared__ float slut[9 * 256];
    __shared__ float seq[256];
    seq[t] = lut_eq[n * 256 + t];
    const float* lt = lut_tile + n * 64 * 256;
    for (int j = t; j < 9 * 256; j += 256) {
        int q = j >> 8;
        int jy = q / 3, jx = q % 3;
        int gy = min(max(ty - 1 + jy, 0), 7);
        int gx = min(max(tx - 1 + jx, 0), 7);
        slut[j] = lt[(gy * 8 + gx) * 256 + (j & 255)];
    }
    __syncthreads();

    const float* img = x + (size_t)n * 3 * HW;
    const unsigned char* lip = li_arr + (size_t)n * HW;
    float* o0 = out + (size_t)n * 3 * HW;
    float* o1 = out + (size_t)3 * NHW + (size_t)n * 3 * HW;

    for (int it = 0; it < 4; it++) {
        int j = it * 1024 + t * 4;          // flattened tile index, 4 consecutive px
        int r = j >> 6, c = j & 63;
        int y = ty * TILE + r;
        int xb = tx * TILE + c;
        int p = y * WW + xb;

        float4 r4 = *(const float4*)(img + p);
        float4 g4 = *(const float4*)(img + HW + p);
        float4 b4 = *(const float4*)(img + 2 * HW + p);
        uchar4 li4 = *(const uchar4*)(lip + p);

        float cyf = fminf(fmaxf(((float)y + 0.5f) / 64.0f - 0.5f, 0.0f), 7.0f);
        int y0 = min((int)cyf, 6);
        float wy = cyf - (float)y0;
        int ly = y0 - ty + 1;

        float4 R0, G0, B0, R1, G1, B1;
        #pragma unroll
        for (int k = 0; k < 4; k++) {
            float rr = ((const float*)&r4)[k];
            float gg = ((const float*)&g4)[k];
            float bb = ((const float*)&b4)[k];
            float rl = srgb2lin_p(rr), gl = srgb2lin_p(gg), bl = srgb2lin_p(bb);
            float X = ((float)0.4124564 * rl + (float)0.3575761 * gl + (float)0.1804375 * bl) / (float)0.95047;
            float Y = ((float)0.2126729 * rl + (float)0.7151522 * gl + (float)0.072175  * bl);
            float Z = ((float)0.0193339 * rl + (float)0.119192  * gl + (float)0.9503041 * bl) / (float)1.08883;
            float fx = fwd_p(X), fy = fwd_p(Y), fz = fwd_p(Z);
            float A  = 500.0f * (fx - fy);
            float B2 = 200.0f * (fy - fz);

            int li = ((const unsigned char*)&li4)[k];
            float l_eq = seq[li];

            int xc = xb + k;
            float cxf = fminf(fmaxf(((float)xc + 0.5f) / 64.0f - 0.5f, 0.0f), 7.0f);
            int x0 = min((int)cxf, 6);
            float wx = cxf - (float)x0;
            int lx = x0 - tx + 1;
            int base = ((ly * 3 + lx) << 8) + li;
            float v00 = slut[base];
            float v01 = slut[base + 256];
            float v10 = slut[base + 768];
            float v11 = slut[base + 1024];
            float top = v00 * (1.0f - wx) + v01 * wx;
            float bot = v10 * (1.0f - wx) + v11 * wx;
            float l_cl = top * (1.0f - wy) + bot * wy;

            float R, G, B;
            lab2rgb255_f(l_eq * (float)(100.0 / 255.0), A, B2, &R, &G, &B);
            ((float*)&R0)[k] = R; ((float*)&G0)[k] = G; ((float*)&B0)[k] = B;
            lab2rgb255_f(l_cl * (float)(100.0 / 255.0), A, B2, &R, &G, &B);
            ((float*)&R1)[k] = R; ((float*)&G1)[k] = G; ((float*)&B1)[k] = B;
        }
        *(float4*)(o0 + p)          = R0;
        *(float4*)(o0 + HW + p)     = G0;
        *(float4*)(o0 + 2 * HW + p) = B0;
        *(float4*)(o1 + p)          = R1;
        *(float4*)(o1 + HW + p)     = G1;
        *(float4*)(o1 + 2 * HW + p) = B1;
    }
}

extern "C" void kernel_launch(void* const* d_in, const int* in_sizes, int n_in,
                              void* d_out, int out_size, void* d_ws, size_t ws_size,
                              hipStream_t stream) {
    const float* x = (const float*)d_in[0];
    float* out = (float*)d_out;
    char* ws = (char*)d_ws;

    float* Lbuf = (float*)ws;                             // 16.8 MiB
    size_t off = (size_t)NHW * 4;
    unsigned char* li = (unsigned char*)(ws + off); off += NHW;          // 4.2 MiB
    int* hist_tile = (int*)(ws + off);    off += NIMG * 64 * 256 * 4;    // 1 MiB
    float* lut_eq = (float*)(ws + off);   off += NIMG * 256 * 4;
    float* lut_tile = (float*)(ws + off); off += NIMG * 64 * 256 * 4;    // 1 MiB
    unsigned* mm = (unsigned*)(ws + off); off += NIMG * 64 * 4;

    k_init<<<4, 256, 0, stream>>>(mm);
    k_lab<<<dim3(HW / 2048, NIMG), 256, 0, stream>>>(x, Lbuf, mm);
    k_quant_hist<<<dim3(64, NIMG), 256, 0, stream>>>(Lbuf, mm, li, hist_tile, lut_tile);
    k_eq_lut<<<NIMG, 256, 0, stream>>>(hist_tile, lut_eq);
    k_recon<<<dim3(64, NIMG), 256, 0, stream>>>(x, li, lut_eq, lut_tile, out);
}

// Round 6
// 171.204 us; speedup vs baseline: 3.1562x; 1.0845x over previous
//
#include <hip/hip_runtime.h>

#define NIMG 16
#define HH 512
#define WW 512
#define HW (HH * WW)
#define NHW (NIMG * HW)
#define TILE 64
#define TILE_AREA (TILE * TILE)

#define EPSV ((float)(216.0 / 24389.0))
#define KAPV ((float)(24389.0 / 27.0))

// ---------- fast transcendental helpers ----------

__device__ __forceinline__ float pow24(float t) {
    float l   = __builtin_amdgcn_logf(t);
    float r   = __builtin_amdgcn_exp2f(l);
    float dl  = (t - r) * __builtin_amdgcn_rcpf(r) * 1.4426950408889634f;
    float ehi = 2.4f * l;
    float elo = __builtin_fmaf(2.4f, l, -ehi) + 2.4f * dl;
    float p   = __builtin_amdgcn_exp2f(ehi);
    return __builtin_fmaf(p * 0.6931471805599453f, elo, p);
}

__device__ __forceinline__ float cbrt_p(float v) {
    float l  = __builtin_amdgcn_logf(v);
    float t  = __builtin_amdgcn_exp2f(l * (1.0f / 3.0f));
    float t2 = t * t;
    float num = __builtin_fmaf(-t2, t, v);
    return __builtin_fmaf(num, __builtin_amdgcn_rcpf(3.0f * t2), t);
}

__device__ __forceinline__ float srgb2lin_p(float c) {
    float lin = c / 12.92f;
    float t   = (c + 0.055f) / 1.055f;
    return (c <= 0.04045f) ? lin : pow24(t);
}

__device__ __forceinline__ float fwd_p(float v) {
    return (v > EPSV) ? cbrt_p(v) : (KAPV * v + 16.0f) / 116.0f;
}

__device__ __forceinline__ float lin2srgb_f(float c) {
    c = fmaxf(c, 0.0f);
    float lo = c * 12.92f;
    float p  = __builtin_amdgcn_exp2f(__builtin_amdgcn_logf(c) * (float)(1.0 / 2.4));
    float hi = 1.055f * p - 0.055f;
    float r  = (c <= 0.0031308f) ? lo : hi;
    return fminf(fmaxf(r, 0.0f), 1.0f);
}

__device__ __forceinline__ float finv_f(float f) {
    float f3 = f * f * f;
    return (f3 > EPSV) ? f3 : (116.0f * f - 16.0f) * (float)(27.0 / 24389.0);
}

__device__ __forceinline__ void lab2rgb255_f(float L, float a, float b,
                                             float* R, float* G, float* B) {
    float fy = (L + 16.0f) * (float)(1.0 / 116.0);
    float fx = fy + a * (float)(1.0 / 500.0);
    float fz = fy - b * (float)(1.0 / 200.0);
    float X = finv_f(fx) * 0.95047f;
    float Y = finv_f(fy);
    float Z = finv_f(fz) * 1.08883f;
    *R = lin2srgb_f((float)3.2404542 * X + (float)-1.5371385 * Y + (float)-0.4985314 * Z) * 255.0f;
    *G = lin2srgb_f((float)-0.969266 * X + (float)1.8760108  * Y + (float)0.041556   * Z) * 255.0f;
    *B = lin2srgb_f((float)0.0556434 * X + (float)-0.2040259 * Y + (float)1.0572252  * Z) * 255.0f;
}

// K1: one block per 64x64 tile. Lab once; L -> Lbuf; a,b -> out0 ch1/ch2
// (scratch; K3's same thread reads before overwriting). Tile min/max ->
// tmn/tmx[b] with plain stores (no atomics).
__global__ void k1_lab(const float* __restrict__ x, float* __restrict__ Lbuf,
                       float* __restrict__ out, float* __restrict__ tmn,
                       float* __restrict__ tmx) {
    int n = blockIdx.y, tile = blockIdx.x;
    int b = (n << 6) + tile;
    int ty = tile >> 3, tx = tile & 7;
    int t = threadIdx.x;
    const float* img = x + (size_t)n * 3 * HW;
    float* Lp = Lbuf + (size_t)n * HW;
    float* o0 = out + (size_t)n * 3 * HW;

    float mn = 1e30f, mx = -1e30f;
    #pragma unroll
    for (int it = 0; it < 4; it++) {
        int j = it * 1024 + t * 4;
        int r = j >> 6, c = j & 63;
        int p = (ty * TILE + r) * WW + tx * TILE + c;
        float4 r4 = *(const float4*)(img + p);
        float4 g4 = *(const float4*)(img + HW + p);
        float4 b4 = *(const float4*)(img + 2 * HW + p);
        float4 L4, A4, B4;
        #pragma unroll
        for (int k = 0; k < 4; k++) {
            float rr = ((const float*)&r4)[k];
            float gg = ((const float*)&g4)[k];
            float bb = ((const float*)&b4)[k];
            float rl = srgb2lin_p(rr), gl = srgb2lin_p(gg), bl = srgb2lin_p(bb);
            float X = ((float)0.4124564 * rl + (float)0.3575761 * gl + (float)0.1804375 * bl) / (float)0.95047;
            float Y = ((float)0.2126729 * rl + (float)0.7151522 * gl + (float)0.072175  * bl);
            float Z = ((float)0.0193339 * rl + (float)0.119192  * gl + (float)0.9503041 * bl) / (float)1.08883;
            float fx = fwd_p(X), fy = fwd_p(Y), fz = fwd_p(Z);
            float L = 116.0f * fy - 16.0f;
            ((float*)&L4)[k] = L;
            ((float*)&A4)[k] = 500.0f * (fx - fy);
            ((float*)&B4)[k] = 200.0f * (fy - fz);
            mn = fminf(mn, L);
            mx = fmaxf(mx, L);
        }
        *(float4*)(Lp + p)          = L4;
        *(float4*)(o0 + HW + p)     = A4;
        *(float4*)(o0 + 2 * HW + p) = B4;
    }
    for (int off = 32; off; off >>= 1) {
        mn = fminf(mn, __shfl_down(mn, off, 64));
        mx = fmaxf(mx, __shfl_down(mx, off, 64));
    }
    __shared__ float smn[4], smx[4];
    int wv = t >> 6, ln = t & 63;
    if (ln == 0) { smn[wv] = mn; smx[wv] = mx; }
    __syncthreads();
    if (t == 0) {
        tmn[b] = fminf(fminf(smn[0], smn[1]), fminf(smn[2], smn[3]));
        tmx[b] = fmaxf(fmaxf(smx[0], smx[1]), fmaxf(smx[2], smx[3]));
    }
}

// K2: per tile: reduce image min/max from 64 tile entries, quantize L,
// store li (uchar4), LDS hist, tile hist + CLAHE LUT (exact int scan).
__global__ void k2_quant(const float* __restrict__ Lbuf, const float* __restrict__ tmn,
                         const float* __restrict__ tmx, unsigned char* __restrict__ li_arr,
                         int* __restrict__ hist_tile, float* __restrict__ lut_tile) {
    int n = blockIdx.y, tile = blockIdx.x;
    int b = (n << 6) + tile;
    int ty = tile >> 3, tx = tile & 7;
    int t = threadIdx.x;

    __shared__ int sh[256];
    __shared__ float sred2[2];
    __shared__ int wsum[4];

    if (t < 64) {
        float v = tmn[(n << 6) + t];
        for (int off = 32; off; off >>= 1) v = fminf(v, __shfl_down(v, off, 64));
        if (t == 0) sred2[0] = v;
    } else if (t < 128) {
        float v = tmx[(n << 6) + (t - 64)];
        for (int off = 32; off; off >>= 1) v = fmaxf(v, __shfl_down(v, off, 64));
        if (t == 64) sred2[1] = v;
    }
    sh[t] = 0;
    __syncthreads();
    float lmin = sred2[0], lmax = sred2[1];
    float d = lmax - lmin + (float)1e-6;

    const float* Lp = Lbuf + (size_t)n * HW;
    unsigned char* lio = li_arr + (size_t)n * HW;
    #pragma unroll
    for (int it = 0; it < 4; it++) {
        int j = it * 1024 + t * 4;
        int r = j >> 6, c = j & 63;
        int p = (ty * TILE + r) * WW + tx * TILE + c;
        float4 L4 = *(const float4*)(Lp + p);
        uchar4 li4;
        #pragma unroll
        for (int k = 0; k < 4; k++) {
            float l255 = (((const float*)&L4)[k] - lmin) / d * 255.0f;
            int li = (int)rintf(l255);
            li = min(max(li, 0), 255);
            ((unsigned char*)&li4)[k] = (unsigned char)li;
            atomicAdd(&sh[li], 1);
        }
        *(uchar4*)(lio + p) = li4;
    }
    __syncthreads();
    int h = sh[t];
    hist_tile[b * 256 + t] = h;

    int cl = min(h, 32);   // limit = max(2*4096/256, 1) = 32
    int sum = cl;
    for (int off = 32; off; off >>= 1) sum += __shfl_down(sum, off, 64);
    int wv = t >> 6, ln = t & 63;
    if (ln == 0) wsum[wv] = sum;
    __syncthreads();
    int total = wsum[0] + wsum[1] + wsum[2] + wsum[3];
    int exc = TILE_AREA - total;
    sh[t] = 256 * cl + exc;                 // term*256, exact in int
    __syncthreads();
    for (int off = 1; off < 256; off <<= 1) {
        int v = sh[t];
        int add = (t >= off) ? sh[t - off] : 0;
        __syncthreads();
        sh[t] = v + add;
        __syncthreads();
    }
    lut_tile[b * 256 + t] = rintf((float)sh[t] * (float)(255.0 / 1048576.0));
}

// K3: per tile: eq LUT (redundant per block from L2-resident tile hists),
// 9 neighbor tile LUTs in LDS, read li + a,b, write both outputs.
__global__ void k3_recon(const unsigned char* __restrict__ li_arr,
                         const int* __restrict__ hist_tile,
                         const float* __restrict__ lut_tile,
                         float* out) {
    int n = blockIdx.y, tile = blockIdx.x;
    int ty = tile >> 3, tx = tile & 7;
    int t = threadIdx.x;

    __shared__ int   sscan[256];
    __shared__ float seq[256];
    __shared__ float slut[9 * 256];

    const int* ht = hist_tile + n * 64 * 256;
    int h2 = 0;
    for (int tile2 = 0; tile2 < 64; tile2++) h2 += ht[tile2 * 256 + t];
    sscan[t] = h2;
    __syncthreads();
    for (int off = 1; off < 256; off <<= 1) {
        int v = sscan[t];
        int add = (t >= off) ? sscan[t - off] : 0;
        __syncthreads();
        sscan[t] = v + add;
        __syncthreads();
    }
    seq[t] = rintf((float)sscan[t] * (float)(255.0 / (double)HW));

    const float* lt = lut_tile + n * 64 * 256;
    for (int j = t; j < 9 * 256; j += 256) {
        int q = j >> 8;
        int jy = q / 3, jx = q % 3;
        int gy = min(max(ty - 1 + jy, 0), 7);
        int gx = min(max(tx - 1 + jx, 0), 7);
        slut[j] = lt[(gy * 8 + gx) * 256 + (j & 255)];
    }
    __syncthreads();

    const unsigned char* lip = li_arr + (size_t)n * HW;
    float* o0 = out + (size_t)n * 3 * HW;
    float* o1 = out + (size_t)3 * NHW + (size_t)n * 3 * HW;

    #pragma unroll
    for (int it = 0; it < 4; it++) {
        int j = it * 1024 + t * 4;
        int r = j >> 6, c = j & 63;
        int y = ty * TILE + r;
        int xb = tx * TILE + c;
        int p = y * WW + xb;

        uchar4 li4 = *(const uchar4*)(lip + p);
        float4 a4 = *(const float4*)(o0 + HW + p);       // a (from K1)
        float4 b4 = *(const float4*)(o0 + 2 * HW + p);   // b (from K1)

        float cyf = fminf(fmaxf(((float)y + 0.5f) / 64.0f - 0.5f, 0.0f), 7.0f);
        int y0 = min((int)cyf, 6);
        float wy = cyf - (float)y0;
        int ly = y0 - ty + 1;

        float4 R0, G0, B0, R1, G1, B1;
        #pragma unroll
        for (int k = 0; k < 4; k++) {
            int li = ((const unsigned char*)&li4)[k];
            float A  = ((const float*)&a4)[k];
            float B2 = ((const float*)&b4)[k];
            float l_eq = seq[li];

            int xc = xb + k;
            float cxf = fminf(fmaxf(((float)xc + 0.5f) / 64.0f - 0.5f, 0.0f), 7.0f);
            int x0 = min((int)cxf, 6);
            float wx = cxf - (float)x0;
            int lx = x0 - tx + 1;
            int base = ((ly * 3 + lx) << 8) + li;
            float v00 = slut[base];
            float v01 = slut[base + 256];
            float v10 = slut[base + 768];
            float v11 = slut[base + 1024];
            float top = v00 * (1.0f - wx) + v01 * wx;
            float bot = v10 * (1.0f - wx) + v11 * wx;
            float l_cl = top * (1.0f - wy) + bot * wy;

            float R, G, B;
            lab2rgb255_f(l_eq * (float)(100.0 / 255.0), A, B2, &R, &G, &B);
            ((float*)&R0)[k] = R; ((float*)&G0)[k] = G; ((float*)&B0)[k] = B;
            lab2rgb255_f(l_cl * (float)(100.0 / 255.0), A, B2, &R, &G, &B);
            ((float*)&R1)[k] = R; ((float*)&G1)[k] = G; ((float*)&B1)[k] = B;
        }
        *(float4*)(o0 + p)          = R0;
        *(float4*)(o0 + HW + p)     = G0;
        *(float4*)(o0 + 2 * HW + p) = B0;
        *(float4*)(o1 + p)          = R1;
        *(float4*)(o1 + HW + p)     = G1;
        *(float4*)(o1 + 2 * HW + p) = B1;
    }
}

extern "C" void kernel_launch(void* const* d_in, const int* in_sizes, int n_in,
                              void* d_out, int out_size, void* d_ws, size_t ws_size,
                              hipStream_t stream) {
    const float* x = (const float*)d_in[0];
    float* out = (float*)d_out;
    char* ws = (char*)d_ws;

    float* Lbuf = (float*)ws;                             // 16.8 MiB
    size_t off = (size_t)NHW * 4;
    unsigned char* li = (unsigned char*)(ws + off); off += NHW;          // 4.2 MiB
    int* hist_tile = (int*)(ws + off);    off += (size_t)NIMG * 64 * 256 * 4;  // 1 MiB
    float* lut_tile = (float*)(ws + off); off += (size_t)NIMG * 64 * 256 * 4;  // 1 MiB
    float* tmn = (float*)(ws + off);      off += 1024 * 4;
    float* tmx = (float*)(ws + off);      off += 1024 * 4;

    dim3 grid(64, NIMG);
    k1_lab<<<grid, 256, 0, stream>>>(x, Lbuf, out, tmn, tmx);
    k2_quant<<<grid, 256, 0, stream>>>(Lbuf, tmn, tmx, li, hist_tile, lut_tile);
    k3_recon<<<grid, 256, 0, stream>>>(li, hist_tile, lut_tile, out);
}